// Round 1
// baseline (156.073 us; speedup 1.0000x reference)
//
#include <hip/hip_runtime.h>
#include <math.h>

// Problem constants (from reference / setup_inputs)
#define N_ROIS   32
#define N_GT     (N_ROIS * 8)      // 256 context boxes
#define N_CAT    (N_ROIS * 9)      // 288 cat_rois rows
#define C_FEAT   256
#define H_FEAT   40
#define W_FEAT   40
#define P_FEAT   (H_FEAT * W_FEAT) // 1600 pixels
#define PH       7
#define PW       7
#define SCALE    0.0625f
#define MIN_SIZE 16.0f
#define CELLS    (PH * PW)                 // 49
#define POOL_PER_BOX (C_FEAT * CELLS)      // 12544
#define OUT_POOL_ELEMS ((size_t)N_CAT * POOL_PER_BOX)  // 3,612,672
// cat_rois output starts at OUT_POOL_ELEMS in d_out (288*5 floats)

// ---------------------------------------------------------------------------
// Kernel 0: transpose features (C, H*W) -> (H*W, C) so channel dim is
// contiguous (coalesced reads in the pool kernel). Classic 32x32 LDS tile.
// grid (P/32=50, C/32=8), block (32,8)
// ---------------------------------------------------------------------------
__global__ void transpose_feat_kernel(const float* __restrict__ f,
                                      float* __restrict__ ft) {
    __shared__ float tile[32][33];   // +1 pad: conflict-free transpose
    const int pt = blockIdx.x * 32;
    const int ct = blockIdx.y * 32;
    const int lx = threadIdx.x;      // 0..31
    const int ly = threadIdx.y;      // 0..7
    #pragma unroll
    for (int i = 0; i < 32; i += 8) {
        // read coalesced along pixels
        tile[ly + i][lx] = f[(ct + ly + i) * P_FEAT + (pt + lx)];
    }
    __syncthreads();
    #pragma unroll
    for (int i = 0; i < 32; i += 8) {
        // write coalesced along channels
        ft[(pt + ly + i) * C_FEAT + (ct + lx)] = tile[lx][ly + i];
    }
}

// ---------------------------------------------------------------------------
// Kernel 1: context anchors + IoU labeling -> cat_rois (288 x 5)
// one block, 256 threads: thread g handles gt box g (g = n*8 + j)
// ---------------------------------------------------------------------------
__global__ void context_rois_kernel(const float* __restrict__ rois,
                                    const int* __restrict__ hh_p,
                                    const int* __restrict__ hw_p,
                                    float* __restrict__ cat_out) {
    __shared__ float R[N_ROIS * 5];  // 160 floats
    const int tid = threadIdx.x;
    if (tid < N_ROIS * 5) R[tid] = rois[tid];
    __syncthreads();

    const float hh = (float)(*hh_p);
    const float hw = (float)(*hw_p);

    const int g = tid;               // 0..255
    const int n = g >> 3;
    const int j = g & 7;
    const int m = (j < 4) ? j : j + 1;   // skip center (index 4) of the 3x3
    const int r  = m / 3;
    const int cc = m % 3;

    const float x1 = R[n * 5 + 1], y1 = R[n * 5 + 2];
    const float x2 = R[n * 5 + 3], y2 = R[n * 5 + 4];
    const float w = x2 - x1, h = y2 - y1;

    // sx[k] = x1 + w*(k-0.5); cx indexed by column cc, cy by row r
    const float cx = x1 + w * ((float)cc - 0.5f);
    const float cy = y1 + h * ((float)r  - 0.5f);
    float bx1 = cx - w * 0.25f;
    float by1 = cy - h * 0.25f;
    float bx2 = cx + w * 0.25f;
    float by2 = cy + h * 0.25f;
    const float bw = bx2 - bx1 + 1.0f;
    const float bh = by2 - by1 + 1.0f;
    const bool invalid = (bx1 < 0.0f) || (by1 < 0.0f) ||
                         (bx2 >= hw) || (by2 >= hh) ||
                         (bw < MIN_SIZE) || (bh < MIN_SIZE);
    if (invalid) { bx1 = x1; by1 = y1; bx2 = x2; by2 = y2; }

    // IoU of this gt box against all 32 anchor rois
    const float gw = bx2 - bx1 + 1.0f;
    const float gh = by2 - by1 + 1.0f;
    const float garea = gw * gh;
    const bool gdeg = (gw == 1.0f) && (gh == 1.0f);

    float best_ov = -INFINITY;
    int best = 0;
    for (int a = 0; a < N_ROIS; ++a) {
        const float ax1 = R[a * 5 + 1], ay1 = R[a * 5 + 2];
        const float ax2 = R[a * 5 + 3], ay2 = R[a * 5 + 4];
        const float aw = ax2 - ax1 + 1.0f, ah = ay2 - ay1 + 1.0f;
        float iw = fminf(ax2, bx2) - fmaxf(ax1, bx1) + 1.0f;
        float ih = fminf(ay2, by2) - fmaxf(ay1, by1) + 1.0f;
        iw = fmaxf(iw, 0.0f);
        ih = fmaxf(ih, 0.0f);
        const float inter = iw * ih;
        float ov = inter / (aw * ah + garea - inter);
        if (gdeg) ov = 0.0f;                       // column mask first
        if (aw == 1.0f && ah == 1.0f) ov = -1.0f;  // row mask overrides
        if (ov > best_ov) { best_ov = ov; best = a; }  // first-max = argmax
    }

    bool label = (best_ov >= 0.3f);
    const float w_cell = bx2 - bx1;
    const float h_cell = by2 - by1;
    const float rw = label ? (R[best * 5 + 3] - R[best * 5 + 1]) : 0.0f;
    const float rh = label ? (R[best * 5 + 4] - R[best * 5 + 2]) : 0.0f;
    label = label &&
            !(fmaxf(rw, rh) >= fmaxf(w_cell, h_cell)) &&
            !(fminf(rw, rh) < fminf(w_cell, h_cell) / 3.0f);
    if (label) {
        bx1 = R[best * 5 + 1]; by1 = R[best * 5 + 2];
        bx2 = R[best * 5 + 3]; by2 = R[best * 5 + 4];
    }

    // cat_rois row n*9 + 1 + j  (gt boxes, col0 = 0)
    float* row = cat_out + (size_t)(n * 9 + 1 + j) * 5;
    row[0] = 0.0f;
    row[1] = bx1; row[2] = by1; row[3] = bx2; row[4] = by2;
    // cat_rois row n*9 (the original roi, verbatim)
    if (j == 0) {
        float* rr = cat_out + (size_t)(n * 9) * 5;
        #pragma unroll
        for (int t = 0; t < 5; ++t) rr[t] = R[n * 5 + t];
    }
}

// ---------------------------------------------------------------------------
// Kernel 2: Caffe max RoIPool. One block per box (288), one thread per
// channel (256). Results staged in LDS, then written contiguously.
// ---------------------------------------------------------------------------
__global__ void roi_pool_kernel(const float* __restrict__ feat,
                                const float* __restrict__ cat_rois,
                                float* __restrict__ out,
                                int transposed) {
    const int b = blockIdx.x;        // box 0..287
    const int c = threadIdx.x;       // channel 0..255

    const float* cr = cat_rois + (size_t)b * 5;
    const float x1 = cr[1], y1 = cr[2], x2 = cr[3], y2 = cr[4];
    // jnp.round = round-half-to-even = rintf (default rounding mode)
    const float sw = rintf(x1 * SCALE);
    const float sh = rintf(y1 * SCALE);
    const float ew = rintf(x2 * SCALE);
    const float eh = rintf(y2 * SCALE);
    const float bsh = fmaxf(eh - sh + 1.0f, 1.0f) * (1.0f / (float)PH);
    const float bsw = fmaxf(ew - sw + 1.0f, 1.0f) * (1.0f / (float)PW);

    int hs[PH], he[PH], wss[PW], wee[PW];
    #pragma unroll
    for (int i = 0; i < PH; ++i) {
        float lo = floorf((float)i * bsh) + sh;
        float hi = ceilf((float)(i + 1) * bsh) + sh;
        hs[i] = (int)fminf(fmaxf(lo, 0.0f), (float)H_FEAT);
        he[i] = (int)fminf(fmaxf(hi, 0.0f), (float)H_FEAT);
        float wlo = floorf((float)i * bsw) + sw;
        float whi = ceilf((float)(i + 1) * bsw) + sw;
        wss[i] = (int)fminf(fmaxf(wlo, 0.0f), (float)W_FEAT);
        wee[i] = (int)fminf(fmaxf(whi, 0.0f), (float)W_FEAT);
    }

    __shared__ float tile[POOL_PER_BOX];  // 50176 B LDS

    for (int i = 0; i < PH; ++i) {
        for (int j = 0; j < PW; ++j) {
            const bool any = (he[i] > hs[i]) && (wee[j] > wss[j]);
            float mx = -1e30f;
            for (int y = hs[i]; y < he[i]; ++y) {
                for (int x = wss[j]; x < wee[j]; ++x) {
                    const float v = transposed
                        ? feat[(size_t)(y * W_FEAT + x) * C_FEAT + c]
                        : feat[(size_t)c * P_FEAT + y * W_FEAT + x];
                    mx = fmaxf(mx, v);
                }
            }
            tile[c * CELLS + i * PW + j] = any ? mx : 0.0f;
        }
    }
    __syncthreads();

    // coalesced contiguous write: out[b*12544 + (c*49 + cell)]
    float* ob = out + (size_t)b * POOL_PER_BOX;
    for (int t = c; t < POOL_PER_BOX; t += C_FEAT) ob[t] = tile[t];
}

// ---------------------------------------------------------------------------
extern "C" void kernel_launch(void* const* d_in, const int* in_sizes, int n_in,
                              void* d_out, int out_size, void* d_ws, size_t ws_size,
                              hipStream_t stream) {
    const float* features = (const float*)d_in[0];   // (1,256,40,40)
    const float* rois     = (const float*)d_in[1];   // (32,5)
    const int*   hh_p     = (const int*)d_in[2];
    const int*   hw_p     = (const int*)d_in[3];

    float* out      = (float*)d_out;
    float* cat_out  = out + OUT_POOL_ELEMS;          // (288,5) tail of d_out
    float* ft       = (float*)d_ws;                  // transposed features

    const size_t ft_bytes = (size_t)C_FEAT * P_FEAT * sizeof(float);
    const int use_transpose = (ws_size >= ft_bytes) ? 1 : 0;

    if (use_transpose) {
        dim3 tgrid(P_FEAT / 32, C_FEAT / 32);
        dim3 tblock(32, 8);
        hipLaunchKernelGGL(transpose_feat_kernel, tgrid, tblock, 0, stream,
                           features, ft);
    }

    hipLaunchKernelGGL(context_rois_kernel, dim3(1), dim3(256), 0, stream,
                       rois, hh_p, hw_p, cat_out);

    hipLaunchKernelGGL(roi_pool_kernel, dim3(N_CAT), dim3(C_FEAT), 0, stream,
                       use_transpose ? ft : features, cat_out, out,
                       use_transpose);
}

// Round 2
// 88.003 us; speedup vs baseline: 1.7735x; 1.7735x over previous
//
#include <hip/hip_runtime.h>
#include <math.h>

// Problem constants (from reference / setup_inputs)
#define N_ROIS   32
#define N_GT     (N_ROIS * 8)      // 256 context boxes
#define N_CAT    (N_ROIS * 9)      // 288 cat_rois rows
#define C_FEAT   256
#define H_FEAT   40
#define W_FEAT   40
#define P_FEAT   (H_FEAT * W_FEAT) // 1600 pixels
#define PH       7
#define PW       7
#define SCALE    0.0625f
#define MIN_SIZE 16.0f
#define CELLS    (PH * PW)                 // 49
#define POOL_PER_BOX (C_FEAT * CELLS)      // 12544
#define OUT_POOL_ELEMS ((size_t)N_CAT * POOL_PER_BOX)  // 3,612,672

#define N_TRANS_BLOCKS (P_FEAT / 32 * (C_FEAT / 32))   // 50*8 = 400

// ---------------------------------------------------------------------------
// Kernel 0 (fused prep): blocks 0..399 transpose features (C,P)->(P,C);
// block 400 computes context anchors + IoU labeling -> cat_rois (288x5).
// The two halves are independent; fusing saves one launch overhead.
// ---------------------------------------------------------------------------
__global__ void prep_kernel(const float* __restrict__ f,
                            const float* __restrict__ rois,
                            const int* __restrict__ hh_p,
                            const int* __restrict__ hw_p,
                            float* __restrict__ ft,
                            float* __restrict__ cat_out,
                            int use_transpose) {
    __shared__ float tile[32][33];   // transpose tile (+1 pad)
    __shared__ float R[N_ROIS * 5];  // rois stage for context half
    const int bid = blockIdx.x;
    const int tid = threadIdx.x;

    if (bid < N_TRANS_BLOCKS) {
        if (!use_transpose) return;
        const int pt = (bid % (P_FEAT / 32)) * 32;
        const int ct = (bid / (P_FEAT / 32)) * 32;
        const int lx = tid & 31;
        const int ly = tid >> 5;     // 0..7
        #pragma unroll
        for (int i = 0; i < 32; i += 8)
            tile[ly + i][lx] = f[(ct + ly + i) * P_FEAT + (pt + lx)];
        __syncthreads();
        #pragma unroll
        for (int i = 0; i < 32; i += 8)
            ft[(pt + ly + i) * C_FEAT + (ct + lx)] = tile[lx][ly + i];
        return;
    }

    // ---- context-anchor half (one block, 256 threads) ----
    if (tid < N_ROIS * 5) R[tid] = rois[tid];
    __syncthreads();

    const float hh = (float)(*hh_p);
    const float hw = (float)(*hw_p);

    const int g = tid;               // 0..255 -> gt box
    const int n = g >> 3;
    const int j = g & 7;
    const int m = (j < 4) ? j : j + 1;   // skip center of 3x3
    const int r  = m / 3;
    const int cc = m % 3;

    const float x1 = R[n * 5 + 1], y1 = R[n * 5 + 2];
    const float x2 = R[n * 5 + 3], y2 = R[n * 5 + 4];
    const float w = x2 - x1, h = y2 - y1;

    const float cx = x1 + w * ((float)cc - 0.5f);
    const float cy = y1 + h * ((float)r  - 0.5f);
    float bx1 = cx - w * 0.25f;
    float by1 = cy - h * 0.25f;
    float bx2 = cx + w * 0.25f;
    float by2 = cy + h * 0.25f;
    const float bw = bx2 - bx1 + 1.0f;
    const float bh = by2 - by1 + 1.0f;
    const bool invalid = (bx1 < 0.0f) || (by1 < 0.0f) ||
                         (bx2 >= hw) || (by2 >= hh) ||
                         (bw < MIN_SIZE) || (bh < MIN_SIZE);
    if (invalid) { bx1 = x1; by1 = y1; bx2 = x2; by2 = y2; }

    const float gw = bx2 - bx1 + 1.0f;
    const float gh = by2 - by1 + 1.0f;
    const float garea = gw * gh;
    const bool gdeg = (gw == 1.0f) && (gh == 1.0f);

    float best_ov = -INFINITY;
    int best = 0;
    for (int a = 0; a < N_ROIS; ++a) {
        const float ax1 = R[a * 5 + 1], ay1 = R[a * 5 + 2];
        const float ax2 = R[a * 5 + 3], ay2 = R[a * 5 + 4];
        const float aw = ax2 - ax1 + 1.0f, ah = ay2 - ay1 + 1.0f;
        float iw = fminf(ax2, bx2) - fmaxf(ax1, bx1) + 1.0f;
        float ih = fminf(ay2, by2) - fmaxf(ay1, by1) + 1.0f;
        iw = fmaxf(iw, 0.0f);
        ih = fmaxf(ih, 0.0f);
        const float inter = iw * ih;
        float ov = inter / (aw * ah + garea - inter);
        if (gdeg) ov = 0.0f;
        if (aw == 1.0f && ah == 1.0f) ov = -1.0f;
        if (ov > best_ov) { best_ov = ov; best = a; }
    }

    bool label = (best_ov >= 0.3f);
    const float w_cell = bx2 - bx1;
    const float h_cell = by2 - by1;
    const float rw = label ? (R[best * 5 + 3] - R[best * 5 + 1]) : 0.0f;
    const float rh = label ? (R[best * 5 + 4] - R[best * 5 + 2]) : 0.0f;
    label = label &&
            !(fmaxf(rw, rh) >= fmaxf(w_cell, h_cell)) &&
            !(fminf(rw, rh) < fminf(w_cell, h_cell) / 3.0f);
    if (label) {
        bx1 = R[best * 5 + 1]; by1 = R[best * 5 + 2];
        bx2 = R[best * 5 + 3]; by2 = R[best * 5 + 4];
    }

    float* row = cat_out + (size_t)(n * 9 + 1 + j) * 5;
    row[0] = 0.0f;
    row[1] = bx1; row[2] = by1; row[3] = bx2; row[4] = by2;
    if (j == 0) {
        float* rr = cat_out + (size_t)(n * 9) * 5;
        #pragma unroll
        for (int t = 0; t < 5; ++t) rr[t] = R[n * 5 + t];
    }
}

// ---------------------------------------------------------------------------
// Kernel 1: Caffe max RoIPool. One block per (box, pooled-row i): 2016
// blocks x 256 threads (thread = channel) -> ~31.5 waves/CU occupancy.
// j-loop (7 cells) fully unrolled -> 7 independent fmax chains (MLP).
// Loads are block-uniform (y,x) + lane=c -> 1 KB coalesced per wave-load.
// ---------------------------------------------------------------------------
__global__ __launch_bounds__(256) void
roi_pool_kernel(const float* __restrict__ feat,
                const float* __restrict__ cat_rois,
                float* __restrict__ out,
                int transposed) {
    const int b = blockIdx.x / PH;   // box 0..287
    const int i = blockIdx.x % PH;   // pooled row 0..6
    const int c = threadIdx.x;       // channel 0..255

    const float* cr = cat_rois + (size_t)b * 5;
    const float x1 = cr[1], y1 = cr[2], x2 = cr[3], y2 = cr[4];
    // jnp.round = round-half-to-even = rintf (default rounding mode)
    const float sw = rintf(x1 * SCALE);
    const float sh = rintf(y1 * SCALE);
    const float ew = rintf(x2 * SCALE);
    const float eh = rintf(y2 * SCALE);
    const float bsh = fmaxf(eh - sh + 1.0f, 1.0f) * (1.0f / (float)PH);
    const float bsw = fmaxf(ew - sw + 1.0f, 1.0f) * (1.0f / (float)PW);

    const int hs = (int)fminf(fmaxf(floorf((float)i * bsh) + sh, 0.0f), (float)H_FEAT);
    const int he = (int)fminf(fmaxf(ceilf((float)(i + 1) * bsh) + sh, 0.0f), (float)H_FEAT);

    int ws[PW], we[PW];
    #pragma unroll
    for (int j = 0; j < PW; ++j) {
        ws[j] = (int)fminf(fmaxf(floorf((float)j * bsw) + sw, 0.0f), (float)W_FEAT);
        we[j] = (int)fminf(fmaxf(ceilf((float)(j + 1) * bsw) + sw, 0.0f), (float)W_FEAT);
    }

    float mx[PW];
    #pragma unroll
    for (int j = 0; j < PW; ++j) mx[j] = -1e30f;

    for (int y = hs; y < he; ++y) {
        if (transposed) {
            const float* fr = feat + (size_t)(y * W_FEAT) * C_FEAT + c;
            #pragma unroll
            for (int j = 0; j < PW; ++j)
                for (int x = ws[j]; x < we[j]; ++x)
                    mx[j] = fmaxf(mx[j], fr[(size_t)x * C_FEAT]);
        } else {
            const float* fr = feat + (size_t)c * P_FEAT + y * W_FEAT;
            #pragma unroll
            for (int j = 0; j < PW; ++j)
                for (int x = ws[j]; x < we[j]; ++x)
                    mx[j] = fmaxf(mx[j], fr[x]);
        }
    }

    const bool rowv = (he > hs);
    float* ob = out + (size_t)b * POOL_PER_BOX + (size_t)c * CELLS + i * PW;
    #pragma unroll
    for (int j = 0; j < PW; ++j)
        ob[j] = (rowv && (we[j] > ws[j])) ? mx[j] : 0.0f;
}

// ---------------------------------------------------------------------------
extern "C" void kernel_launch(void* const* d_in, const int* in_sizes, int n_in,
                              void* d_out, int out_size, void* d_ws, size_t ws_size,
                              hipStream_t stream) {
    const float* features = (const float*)d_in[0];   // (1,256,40,40)
    const float* rois     = (const float*)d_in[1];   // (32,5)
    const int*   hh_p     = (const int*)d_in[2];
    const int*   hw_p     = (const int*)d_in[3];

    float* out      = (float*)d_out;
    float* cat_out  = out + OUT_POOL_ELEMS;          // (288,5) tail of d_out
    float* ft       = (float*)d_ws;                  // transposed features

    const size_t ft_bytes = (size_t)C_FEAT * P_FEAT * sizeof(float);
    const int use_transpose = (ws_size >= ft_bytes) ? 1 : 0;

    hipLaunchKernelGGL(prep_kernel, dim3(N_TRANS_BLOCKS + 1), dim3(256), 0, stream,
                       features, rois, hh_p, hw_p, ft, cat_out, use_transpose);

    hipLaunchKernelGGL(roi_pool_kernel, dim3(N_CAT * PH), dim3(C_FEAT), 0, stream,
                       use_transpose ? ft : features, cat_out, out,
                       use_transpose);
}